// Round 12
// baseline (764.592 us; speedup 1.0000x reference)
//
#include <hip/hip_runtime.h>
#include <hip/hip_cooperative_groups.h>
#include <stdint.h>

namespace cg = cooperative_groups;

// GraphAttention: B=2, N=4096, C=256, H=4, D=64. Inputs fp32, adj int32,
// OUTPUT FP32 (proven r6/r7). Threshold = 2% of ref absmax = 0.0609.
#define CDIM 256
#define HEADS 4
#define HD 64
#define NB 2
#define NN 4096

typedef unsigned short u16;
typedef unsigned long long u64;
typedef __attribute__((ext_vector_type(8))) short short8;   // bf16x8 frag
typedef __attribute__((ext_vector_type(4))) float f32x4;    // C/D frag

// 0.125 (1/sqrt(64)) * log2(e): folded into Q so softmax uses exp2
#define QSCALE 0.1803368801111244f

__device__ __forceinline__ u16 f2bf(float f) {  // RNE
  union { float f; unsigned u; } v; v.f = f;
  return (u16)((v.u + 0x7fffu + ((v.u >> 16) & 1u)) >> 16);
}
__device__ __forceinline__ float bf2f(u16 u) {
  union { unsigned u; float f; } v; v.u = ((unsigned)u) << 16; return v.f;
}
// load MFMA frag from fp32 global, converting to bf16 in-reg
__device__ __forceinline__ short8 fragf32(const float* p) {
  float4 a = reinterpret_cast<const float4*>(p)[0];
  float4 b = reinterpret_cast<const float4*>(p)[1];
  short8 h;
  h[0] = (short)f2bf(a.x); h[1] = (short)f2bf(a.y);
  h[2] = (short)f2bf(a.z); h[3] = (short)f2bf(a.w);
  h[4] = (short)f2bf(b.x); h[5] = (short)f2bf(b.y);
  h[6] = (short)f2bf(b.z); h[7] = (short)f2bf(b.w);
  return h;
}

// ---------------------------------------------------------------------------
// Unit: adj bitmask for original block-index u in [0,16384).
// bm[(b*N+row)*64 + key/64], bit (key&63).
// ---------------------------------------------------------------------------
__device__ __forceinline__ void adj_unit(int u, const int* __restrict__ adj,
                                         u64* __restrict__ bm) {
  const int wave = threadIdx.x >> 6, lane = threadIdx.x & 63;
  const size_t widx = (size_t)u * 4 + wave;
  const size_t base = widx * 512;
#pragma unroll
  for (int it = 0; it < 8; ++it) {
    int a = adj[base + it * 64 + lane];
    u64 m = __ballot(a != 0);
    if (lane == 0) bm[widx * 8 + it] = m;
  }
}

// ---------------------------------------------------------------------------
// Unit: weight fp32->bf16 conversion, bi in [0,128).
// ---------------------------------------------------------------------------
__device__ __forceinline__ void wconv_unit(
    int bi, const float* __restrict__ Wq, const float* __restrict__ Wk,
    const float* __restrict__ Wv, const float* __restrict__ Wo,
    u16* __restrict__ Wqb, u16* __restrict__ Wkb,
    u16* __restrict__ Wvb, u16* __restrict__ Wob) {
  size_t base = ((size_t)bi * 256 + threadIdx.x) * 8;  // < 262144
  int w = (int)(base >> 16);
  size_t lo = base & 65535;
  const float* src;
  u16* dst;
  if (w == 0)      { src = Wq + lo; dst = Wqb + lo; }
  else if (w == 1) { src = Wk + lo; dst = Wkb + lo; }
  else if (w == 2) { src = Wv + lo; dst = Wvb + lo; }
  else             { src = Wo + lo; dst = Wob + lo; }
  *reinterpret_cast<short8*>(dst) = fragf32(src);
}

// ---------------------------------------------------------------------------
// Unit: QKV projection (MFMA). ym in {0,1,2}, bx in [0,512).
// y=0: Qb=(x@Wq^T+bq)*QSCALE; y=1: Kb=x@Wk^T+bk; y=2: Vtb[bh][d][n]=Wv@x^T+bv.
// ---------------------------------------------------------------------------
__device__ __forceinline__ void qkv_unit(
    int ym, int bx, const float* __restrict__ x,
    const u16* __restrict__ Wqb, const u16* __restrict__ Wkb,
    const u16* __restrict__ Wvb,
    const float* __restrict__ bq, const float* __restrict__ bk,
    const float* __restrict__ bv,
    u16* __restrict__ Qb, u16* __restrict__ Kb, u16* __restrict__ Vtb) {
  const int tid = threadIdx.x, w = tid >> 6, lane = tid & 63;
  const int quad = lane >> 4, l15 = lane & 15;
  const int tok0 = bx * 16;
  const int b = tok0 >> 12, nl = tok0 & 4095;

  f32x4 acc[4];
#pragma unroll
  for (int i = 0; i < 4; ++i) acc[i] = (f32x4){0.f, 0.f, 0.f, 0.f};

  if (ym < 2) {
    const u16* Wb = (ym == 0) ? Wqb : Wkb;
    const float* bias = (ym == 0) ? bq : bk;
    const float scale = (ym == 0) ? QSCALE : 1.0f;
    u16* outp = (ym == 0) ? Qb : Kb;
#pragma unroll
    for (int ks = 0; ks < 8; ++ks) {
      short8 af = fragf32(x + (size_t)(tok0 + l15) * 256 + ks * 32 + quad * 8);
#pragma unroll
      for (int ns = 0; ns < 4; ++ns) {
        short8 bf = *reinterpret_cast<const short8*>(
            &Wb[(size_t)(w * 64 + ns * 16 + l15) * 256 + ks * 32 + quad * 8]);
        acc[ns] = __builtin_amdgcn_mfma_f32_16x16x32_bf16(af, bf, acc[ns], 0, 0, 0);
      }
    }
#pragma unroll
    for (int ns = 0; ns < 4; ++ns) {
      int d = ns * 16 + l15;
      float bb = bias[w * 64 + d];
#pragma unroll
      for (int r = 0; r < 4; ++r) {
        int tok = nl + quad * 4 + r;
        outp[((size_t)(b * HEADS + w) * NN + tok) * HD + d] =
            f2bf((acc[ns][r] + bb) * scale);
      }
    }
  } else {
#pragma unroll
    for (int ks = 0; ks < 8; ++ks) {
      short8 xf = fragf32(x + (size_t)(tok0 + l15) * 256 + ks * 32 + quad * 8);
#pragma unroll
      for (int ms = 0; ms < 4; ++ms) {
        short8 wf = *reinterpret_cast<const short8*>(
            &Wvb[(size_t)(w * 64 + ms * 16 + l15) * 256 + ks * 32 + quad * 8]);
        acc[ms] = __builtin_amdgcn_mfma_f32_16x16x32_bf16(wf, xf, acc[ms], 0, 0, 0);
      }
    }
#pragma unroll
    for (int ms = 0; ms < 4; ++ms) {
#pragma unroll
      for (int r = 0; r < 4; ++r) {
        int d = ms * 16 + quad * 4 + r;
        float bb = bv[w * 64 + d];
        Vtb[((size_t)((b * HEADS + w) * HD + d)) * NN + nl + l15] =
            f2bf(acc[ms][r] + bb);
      }
    }
  }
}

// ---------------------------------------------------------------------------
// Unit: attention (r11 body). bx in [0,64), bh in [0,8), half in {0,1}.
// smem layout: Ks[64*72] u16 | Vs[64*72] u16 | Ps[4][16*72] u16 = 27648 B.
// ---------------------------------------------------------------------------
__device__ __forceinline__ void attn_unit(
    int bx, int bh, int half, char* smem,
    const u16* __restrict__ Qb, const u16* __restrict__ Kb,
    const u16* __restrict__ Vtb, const u64* __restrict__ bm,
    u16* __restrict__ Opb, float* __restrict__ Lp) {
  u16* Ks = (u16*)smem;
  u16* Vs = Ks + 64 * 72;
  u16* Ps = Vs + 64 * 72;

  const int tid = threadIdx.x;
  const int wave = tid >> 6, lane = tid & 63;
  const int quad = lane >> 4, l15 = lane & 15;
  const int b = bh >> 2, h = bh & 3;
  const int q0 = bx * 64 + wave * 16;
  const int key0 = half * 2048;

  const u16* qr = Qb + ((size_t)bh * NN + q0 + l15) * HD + quad * 8;
  const short8 qf0 = *reinterpret_cast<const short8*>(qr);
  const short8 qf1 = *reinterpret_cast<const short8*>(qr + 32);

  f32x4 Oacc[4];
#pragma unroll
  for (int i = 0; i < 4; ++i) Oacc[i] = (f32x4){0.f, 0.f, 0.f, 0.f};
  float li[4] = {0.f, 0.f, 0.f, 0.f};
  const f32x4 z4 = {0.f, 0.f, 0.f, 0.f};
  u16* Pw = Ps + wave * 16 * 72;
  const u64* bmr = bm + ((size_t)b * NN + q0 + quad * 4) * 64 + half * 32;

  const u16* kbase = Kb + (size_t)bh * NN * HD;
  const u16* vbase = Vtb + (size_t)bh * HD * NN;
  const int rr = tid >> 3, cc8 = (tid & 7) * 8;
  const int rr2 = rr + 32;

  uint4 k0, k1, v0, v1;  // prefetch registers (tile 0)
  k0 = *reinterpret_cast<const uint4*>(kbase + (size_t)(key0 + rr) * HD + cc8);
  k1 = *reinterpret_cast<const uint4*>(kbase + (size_t)(key0 + rr2) * HD + cc8);
  v0 = *reinterpret_cast<const uint4*>(vbase + (size_t)rr * NN + key0 + cc8);
  v1 = *reinterpret_cast<const uint4*>(vbase + (size_t)rr2 * NN + key0 + cc8);

  for (int mt = 0; mt < 32; ++mt) {
    __syncthreads();
    *reinterpret_cast<uint4*>(&Ks[rr * 72 + cc8]) = k0;
    *reinterpret_cast<uint4*>(&Ks[rr2 * 72 + cc8]) = k1;
    *reinterpret_cast<uint4*>(&Vs[rr * 72 + cc8]) = v0;
    *reinterpret_cast<uint4*>(&Vs[rr2 * 72 + cc8]) = v1;
    __syncthreads();
    if (mt + 1 < 32) {
      int kb2 = key0 + (mt + 1) * 64;
      k0 = *reinterpret_cast<const uint4*>(kbase + (size_t)(kb2 + rr) * HD + cc8);
      k1 = *reinterpret_cast<const uint4*>(kbase + (size_t)(kb2 + rr2) * HD + cc8);
      v0 = *reinterpret_cast<const uint4*>(vbase + (size_t)rr * NN + kb2 + cc8);
      v1 = *reinterpret_cast<const uint4*>(vbase + (size_t)rr2 * NN + kb2 + cc8);
    }

    u64 am[4];
#pragma unroll
    for (int r = 0; r < 4; ++r) am[r] = bmr[r * 64 + mt];

    // ---- QK^T + mask + exp2 + P ----
#pragma unroll
    for (int t = 0; t < 4; ++t) {
      const u16* kr = &Ks[(t * 16 + l15) * 72 + quad * 8];
      short8 kf0 = *reinterpret_cast<const short8*>(kr);
      short8 kf1 = *reinterpret_cast<const short8*>(kr + 32);
      f32x4 s = __builtin_amdgcn_mfma_f32_16x16x32_bf16(qf0, kf0, z4, 0, 0, 0);
      s = __builtin_amdgcn_mfma_f32_16x16x32_bf16(qf1, kf1, s, 0, 0, 0);
      const int sh = t * 16 + l15;
#pragma unroll
      for (int r = 0; r < 4; ++r) {
        float p = ((unsigned)(am[r] >> sh) & 1u) ? exp2f(s[r]) : 0.f;
        li[r] += p;
        Pw[(quad * 4 + r) * 72 + sh] = (u16)(__float_as_uint(p) >> 16);
      }
    }
    __asm__ volatile("s_waitcnt lgkmcnt(0)" ::: "memory");

    // ---- PV ----
    const short8 pf0 = *reinterpret_cast<const short8*>(&Pw[l15 * 72 + quad * 8]);
    const short8 pf1 = *reinterpret_cast<const short8*>(&Pw[l15 * 72 + 32 + quad * 8]);
#pragma unroll
    for (int dt = 0; dt < 4; ++dt) {
      const u16* vr = &Vs[(dt * 16 + l15) * 72 + quad * 8];
      short8 vf0 = *reinterpret_cast<const short8*>(vr);
      short8 vf1 = *reinterpret_cast<const short8*>(vr + 32);
      Oacc[dt] = __builtin_amdgcn_mfma_f32_16x16x32_bf16(pf0, vf0, Oacc[dt], 0, 0, 0);
      Oacc[dt] = __builtin_amdgcn_mfma_f32_16x16x32_bf16(pf1, vf1, Oacc[dt], 0, 0, 0);
    }
  }

  u16* ob = Opb + (size_t)(half * NB + (bh >> 2)) * NN * CDIM;
#pragma unroll
  for (int r = 0; r < 4; ++r) {
    float lt = li[r];
#pragma unroll
    for (int off = 1; off < 16; off <<= 1) lt += __shfl_xor(lt, off, 64);
    int tok = q0 + quad * 4 + r;
    if (l15 == 0) Lp[((size_t)half * 8 + bh) * NN + tok] = lt;
#pragma unroll
    for (int dt = 0; dt < 4; ++dt)
      ob[(size_t)tok * CDIM + h * HD + dt * 16 + l15] = f2bf(Oacc[dt][r]);
  }
}

// ---------------------------------------------------------------------------
// Unit: combine halves + output projection + LayerNorm. bx in [0,512).
// smem layout: As[16*264] u16 (8448) | ys[16*264] f32 (16896) | linv[64] f32.
// ---------------------------------------------------------------------------
__device__ __forceinline__ void comb_unit(
    int bx, char* smem, const u16* __restrict__ Opb,
    const float* __restrict__ Lp, const u16* __restrict__ Wob,
    const float* __restrict__ bo, const float* __restrict__ gamma,
    const float* __restrict__ beta, float* __restrict__ out) {
  u16* As = (u16*)smem;
  float* ys = (float*)(smem + 8448);
  float* linv = (float*)(smem + 8448 + 16896);
  const int tid = threadIdx.x, w = tid >> 6, lane = tid & 63;
  const int quad = lane >> 4, l15 = lane & 15;
  const int tok0 = bx * 16;
  const int b = tok0 >> 12, nl = tok0 & 4095;

  if (tid < 64) {
    int tokr = tid >> 2, hh = tid & 3;
    int bh = b * 4 + hh;
    int n = nl + tokr;
    float s = Lp[(size_t)bh * NN + n] + Lp[(size_t)(8 + bh) * NN + n];
    linv[tokr * 4 + hh] = (s > 0.f) ? (1.f / s) : 0.f;
  }
  __syncthreads();

  {
    int tokr = tid >> 4, ch0 = (tid & 15) * 16;
    size_t base = ((size_t)b * NN + nl + tokr) * CDIM + ch0;
    uint4 a0 = *reinterpret_cast<const uint4*>(Opb + base);
    uint4 a1 = *reinterpret_cast<const uint4*>(Opb + base + 8);
    uint4 c0 = *reinterpret_cast<const uint4*>(Opb + 2097152 + base);
    uint4 c1 = *reinterpret_cast<const uint4*>(Opb + 2097152 + base + 8);
    float inv = linv[tokr * 4 + (ch0 >> 6)];
    unsigned wa[8] = {a0.x, a0.y, a0.z, a0.w, a1.x, a1.y, a1.z, a1.w};
    unsigned wb[8] = {c0.x, c0.y, c0.z, c0.w, c1.x, c1.y, c1.z, c1.w};
    u16 ov[16];
#pragma unroll
    for (int i = 0; i < 8; ++i) {
      float lo = (bf2f((u16)(wa[i] & 0xffffu)) + bf2f((u16)(wb[i] & 0xffffu))) * inv;
      float hi = (bf2f((u16)(wa[i] >> 16)) + bf2f((u16)(wb[i] >> 16))) * inv;
      ov[2 * i] = f2bf(lo);
      ov[2 * i + 1] = f2bf(hi);
    }
    u16* dst = &As[tokr * 264 + ch0];
    *reinterpret_cast<uint4*>(dst) = *reinterpret_cast<uint4*>(ov);
    *reinterpret_cast<uint4*>(dst + 8) = *reinterpret_cast<uint4*>(ov + 8);
  }
  __syncthreads();

  f32x4 acc[4];
#pragma unroll
  for (int i = 0; i < 4; ++i) acc[i] = (f32x4){0.f, 0.f, 0.f, 0.f};
#pragma unroll
  for (int ks = 0; ks < 8; ++ks) {
    short8 af = *reinterpret_cast<const short8*>(&As[l15 * 264 + ks * 32 + quad * 8]);
#pragma unroll
    for (int ns = 0; ns < 4; ++ns) {
      short8 bf = *reinterpret_cast<const short8*>(
          &Wob[(size_t)(w * 64 + ns * 16 + l15) * 256 + ks * 32 + quad * 8]);
      acc[ns] = __builtin_amdgcn_mfma_f32_16x16x32_bf16(af, bf, acc[ns], 0, 0, 0);
    }
  }

#pragma unroll
  for (int ns = 0; ns < 4; ++ns) {
    int ch = w * 64 + ns * 16 + l15;
    float bb = bo[ch];
#pragma unroll
    for (int r = 0; r < 4; ++r) ys[(quad * 4 + r) * 264 + ch] = acc[ns][r] + bb;
  }
  __syncthreads();

  float g[4], bt[4];
#pragma unroll
  for (int i = 0; i < 4; ++i) {
    g[i] = gamma[lane + i * 64];
    bt[i] = beta[lane + i * 64];
  }
#pragma unroll
  for (int rr = 0; rr < 4; ++rr) {
    int r = w * 4 + rr;
    float v[4], s = 0.f, s2 = 0.f;
#pragma unroll
    for (int i = 0; i < 4; ++i) {
      v[i] = ys[r * 264 + lane + i * 64];
      s += v[i];
      s2 = fmaf(v[i], v[i], s2);
    }
#pragma unroll
    for (int off = 32; off > 0; off >>= 1) {
      s += __shfl_xor(s, off, 64);
      s2 += __shfl_xor(s2, off, 64);
    }
    float mu = s * (1.f / 256.f);
    float rs = rsqrtf(s2 * (1.f / 256.f) - mu * mu + 1e-5f);
    float* orow = out + (size_t)(tok0 + r) * 256;
#pragma unroll
    for (int i = 0; i < 4; ++i)
      orow[lane + i * 64] = (v[i] - mu) * rs * g[i] + bt[i];
  }
}

// ---------------------------------------------------------------------------
// Fused cooperative kernel: 1024 blocks x 256 threads (4 blocks/CU).
// A: wconv + adj half 1 | sync | B: qkv + adj half 2 | sync | C: attn |
// sync | D: comb.
// ---------------------------------------------------------------------------
__global__ __launch_bounds__(256, 4) void fused(
    const float* x, const int* adj,
    const float* Wq, const float* bq, const float* Wk, const float* bk,
    const float* Wv, const float* bv, const float* Wo, const float* bo,
    const float* gamma, const float* beta, float* out,
    u16* Wqb, u16* Wkb, u16* Wvb, u16* Wob, u64* bmp,
    u16* Qb, u16* Kb, u16* Vtb, u16* Opb, float* Lp) {
  __shared__ __align__(16) char smem[27648];
  const int blk = blockIdx.x;
  cg::grid_group grid = cg::this_grid();

  // Stage A
  if (blk < 128) wconv_unit(blk, Wq, Wk, Wv, Wo, Wqb, Wkb, Wvb, Wob);
#pragma unroll 1
  for (int i = 0; i < 8; ++i) adj_unit(blk * 8 + i, adj, bmp);
  grid.sync();

  // Stage B
#pragma unroll 1
  for (int u = blk; u < 1536; u += 1024)
    qkv_unit(u >> 9, u & 511, x, Wqb, Wkb, Wvb, bq, bk, bv, Qb, Kb, Vtb);
#pragma unroll 1
  for (int i = 0; i < 8; ++i) adj_unit(8192 + blk * 8 + i, adj, bmp);
  grid.sync();

  // Stage C
  attn_unit(blk & 63, (blk >> 6) & 7, blk >> 9, smem,
            Qb, Kb, Vtb, bmp, Opb, Lp);
  grid.sync();

  // Stage D
  if (blk < 512)
    comb_unit(blk, smem, Opb, Lp, Wob, bo, gamma, beta, out);
}

// --------------------- fallback wrappers (non-cooperative) ------------------
__global__ __launch_bounds__(256) void prep_k(
    const int* adj, u64* bmp, const float* Wq, const float* Wk,
    const float* Wv, const float* Wo, u16* Wqb, u16* Wkb, u16* Wvb, u16* Wob) {
  if (blockIdx.x < 16384) adj_unit(blockIdx.x, adj, bmp);
  else wconv_unit(blockIdx.x - 16384, Wq, Wk, Wv, Wo, Wqb, Wkb, Wvb, Wob);
}
__global__ __launch_bounds__(256) void qkv_k(
    const float* x, const u16* Wqb, const u16* Wkb, const u16* Wvb,
    const float* bq, const float* bk, const float* bv,
    u16* Qb, u16* Kb, u16* Vtb) {
  qkv_unit(blockIdx.y, blockIdx.x, x, Wqb, Wkb, Wvb, bq, bk, bv, Qb, Kb, Vtb);
}
__global__ __launch_bounds__(256) void attn_k(
    const u16* Qb, const u16* Kb, const u16* Vtb, const u64* bmp,
    u16* Opb, float* Lp) {
  __shared__ __align__(16) char smem[27648];
  attn_unit(blockIdx.x, blockIdx.y, blockIdx.z, smem, Qb, Kb, Vtb, bmp, Opb, Lp);
}
__global__ __launch_bounds__(256) void comb_k(
    const u16* Opb, const float* Lp, const u16* Wob, const float* bo,
    const float* gamma, const float* beta, float* out) {
  __shared__ __align__(16) char smem[25600];
  comb_unit(blockIdx.x, smem, Opb, Lp, Wob, bo, gamma, beta, out);
}

// ---------------------------------------------------------------------------
extern "C" void kernel_launch(void* const* d_in, const int* in_sizes, int n_in,
                              void* d_out, int out_size, void* d_ws, size_t ws_size,
                              hipStream_t stream) {
  const float* x     = (const float*)d_in[0];
  const int*   adj   = (const int*)d_in[1];
  const float* Wq    = (const float*)d_in[2];
  const float* bq    = (const float*)d_in[3];
  const float* Wk    = (const float*)d_in[4];
  const float* bk    = (const float*)d_in[5];
  const float* Wv    = (const float*)d_in[6];
  const float* bv    = (const float*)d_in[7];
  const float* Wo    = (const float*)d_in[8];
  const float* bo    = (const float*)d_in[9];
  const float* gamma = (const float*)d_in[10];
  const float* beta  = (const float*)d_in[11];
  float* out = (float*)d_out;

  const size_t PER = (size_t)NB * HEADS * NN * HD;  // 2,097,152
  u16* Wqb = (u16*)d_ws;
  u16* Wkb = Wqb + 65536;
  u16* Wvb = Wkb + 65536;
  u16* Wob = Wvb + 65536;
  u64* bmp = (u64*)(Wob + 65536);        // 4 MB, 8B-aligned
  u16* Qb  = (u16*)(bmp + 524288);
  u16* Kb  = Qb + PER;
  u16* Vtb = Kb + PER;
  u16* Opb = Vtb + PER;                  // 2 x PER bf16
  float* Lp = (float*)(Opb + 2 * PER);   // 65,536 fp32

  const size_t NEED = (size_t)((u16*)(Lp + 65536) - (u16*)d_ws) * sizeof(u16);
  if (ws_size < NEED) return;

  void* args[] = {
      (void*)&x, (void*)&adj, (void*)&Wq, (void*)&bq, (void*)&Wk, (void*)&bk,
      (void*)&Wv, (void*)&bv, (void*)&Wo, (void*)&bo, (void*)&gamma,
      (void*)&beta, (void*)&out, (void*)&Wqb, (void*)&Wkb, (void*)&Wvb,
      (void*)&Wob, (void*)&bmp, (void*)&Qb, (void*)&Kb, (void*)&Vtb,
      (void*)&Opb, (void*)&Lp};
  hipError_t rc = hipLaunchCooperativeKernel(
      (void*)fused, dim3(1024), dim3(256), args, 0, stream);

  if (rc != hipSuccess) {  // fallback: r11-equivalent 4-launch path
    (void)hipGetLastError();  // clear error state
    prep_k<<<dim3(16512), dim3(256), 0, stream>>>(
        adj, bmp, Wq, Wk, Wv, Wo, Wqb, Wkb, Wvb, Wob);
    qkv_k<<<dim3(512, 3), dim3(256), 0, stream>>>(
        x, Wqb, Wkb, Wvb, bq, bk, bv, Qb, Kb, Vtb);
    attn_k<<<dim3(64, 8, 2), dim3(256), 0, stream>>>(
        Qb, Kb, Vtb, bmp, Opb, Lp);
    comb_k<<<dim3(512), dim3(256), 0, stream>>>(
        Opb, Lp, Wob, bo, gamma, beta, out);
  }
}

// Round 13
// 381.233 us; speedup vs baseline: 2.0056x; 2.0056x over previous
//
#include <hip/hip_runtime.h>
#include <stdint.h>

// GraphAttention: B=2, N=4096, C=256, H=4, D=64. Inputs fp32, adj int32,
// OUTPUT FP32 (proven r6/r7). Threshold = 2% of ref absmax = 0.0609.
// Fixed harness overhead ~175us (measured r12: single-dispatch 590 vs 765).
#define CDIM 256
#define HEADS 4
#define HD 64
#define NB 2
#define NN 4096

typedef unsigned short u16;
typedef unsigned long long u64;
typedef __attribute__((ext_vector_type(8))) short short8;   // bf16x8 frag
typedef __attribute__((ext_vector_type(4))) float f32x4;    // C/D frag

// 0.125 (1/sqrt(64)) * log2(e): folded into Q so softmax uses exp2
#define QSCALE 0.1803368801111244f

__device__ __forceinline__ u16 f2bf(float f) {  // RNE
  union { float f; unsigned u; } v; v.f = f;
  return (u16)((v.u + 0x7fffu + ((v.u >> 16) & 1u)) >> 16);
}
__device__ __forceinline__ float bf2f(u16 u) {
  union { unsigned u; float f; } v; v.u = ((unsigned)u) << 16; return v.f;
}
// load MFMA frag from fp32 global, converting to bf16 in-reg
__device__ __forceinline__ short8 fragf32(const float* p) {
  float4 a = reinterpret_cast<const float4*>(p)[0];
  float4 b = reinterpret_cast<const float4*>(p)[1];
  short8 h;
  h[0] = (short)f2bf(a.x); h[1] = (short)f2bf(a.y);
  h[2] = (short)f2bf(a.z); h[3] = (short)f2bf(a.w);
  h[4] = (short)f2bf(b.x); h[5] = (short)f2bf(b.y);
  h[6] = (short)f2bf(b.z); h[7] = (short)f2bf(b.w);
  return h;
}

// ---------------------------------------------------------------------------
// adj bitmask unit, u in [0,16384). bm[(b*N+row)*64 + key/64], bit (key&63).
// ---------------------------------------------------------------------------
__device__ __forceinline__ void adj_unit(int u, const int* __restrict__ adj,
                                         u64* __restrict__ bm) {
  const int wave = threadIdx.x >> 6, lane = threadIdx.x & 63;
  const size_t widx = (size_t)u * 4 + wave;
  const size_t base = widx * 512;
#pragma unroll
  for (int it = 0; it < 8; ++it) {
    int a = adj[base + it * 64 + lane];
    u64 m = __ballot(a != 0);
    if (lane == 0) bm[widx * 8 + it] = m;
  }
}

// ---------------------------------------------------------------------------
// QKV projection unit (MFMA); W read fp32, converted in-reg (no W prepass).
// ym 0: Qb=(x@Wq^T+bq)*QSCALE; 1: Kb=x@Wk^T+bk; 2: Vtb[bh][d][n]=Wv@x^T+bv.
// ---------------------------------------------------------------------------
__device__ __forceinline__ void qkv_unit(
    int ym, int bx, const float* __restrict__ x,
    const float* __restrict__ Wq, const float* __restrict__ Wk,
    const float* __restrict__ Wv,
    const float* __restrict__ bq, const float* __restrict__ bk,
    const float* __restrict__ bv,
    u16* __restrict__ Qb, u16* __restrict__ Kb, u16* __restrict__ Vtb) {
  const int tid = threadIdx.x, w = tid >> 6, lane = tid & 63;
  const int quad = lane >> 4, l15 = lane & 15;
  const int tok0 = bx * 16;
  const int b = tok0 >> 12, nl = tok0 & 4095;

  f32x4 acc[4];
#pragma unroll
  for (int i = 0; i < 4; ++i) acc[i] = (f32x4){0.f, 0.f, 0.f, 0.f};

  if (ym < 2) {
    const float* W = (ym == 0) ? Wq : Wk;
    const float* bias = (ym == 0) ? bq : bk;
    const float scale = (ym == 0) ? QSCALE : 1.0f;
    u16* outp = (ym == 0) ? Qb : Kb;
#pragma unroll
    for (int ks = 0; ks < 8; ++ks) {
      short8 af = fragf32(x + (size_t)(tok0 + l15) * 256 + ks * 32 + quad * 8);
#pragma unroll
      for (int ns = 0; ns < 4; ++ns) {
        short8 bf = fragf32(
            W + (size_t)(w * 64 + ns * 16 + l15) * 256 + ks * 32 + quad * 8);
        acc[ns] = __builtin_amdgcn_mfma_f32_16x16x32_bf16(af, bf, acc[ns], 0, 0, 0);
      }
    }
#pragma unroll
    for (int ns = 0; ns < 4; ++ns) {
      int d = ns * 16 + l15;
      float bb = bias[w * 64 + d];
#pragma unroll
      for (int r = 0; r < 4; ++r) {
        int tok = nl + quad * 4 + r;
        outp[((size_t)(b * HEADS + w) * NN + tok) * HD + d] =
            f2bf((acc[ns][r] + bb) * scale);
      }
    }
  } else {
#pragma unroll
    for (int ks = 0; ks < 8; ++ks) {
      short8 xf = fragf32(x + (size_t)(tok0 + l15) * 256 + ks * 32 + quad * 8);
#pragma unroll
      for (int ms = 0; ms < 4; ++ms) {
        short8 wf = fragf32(
            Wv + (size_t)(w * 64 + ms * 16 + l15) * 256 + ks * 32 + quad * 8);
        acc[ms] = __builtin_amdgcn_mfma_f32_16x16x32_bf16(wf, xf, acc[ms], 0, 0, 0);
      }
    }
#pragma unroll
    for (int ms = 0; ms < 4; ++ms) {
#pragma unroll
      for (int r = 0; r < 4; ++r) {
        int d = ms * 16 + quad * 4 + r;
        float bb = bv[w * 64 + d];
        Vtb[((size_t)((b * HEADS + w) * HD + d)) * NN + nl + l15] =
            f2bf(acc[ms][r] + bb);
      }
    }
  }
}

// ---------------------------------------------------------------------------
// Launch 1: qkv (blocks 0..1535) + adj bitmask (1536..17919) + Wo conv
// (17920..17951). qkv compute hides under adj's 128 MB HBM stream.
// ---------------------------------------------------------------------------
__global__ __launch_bounds__(256) void l1_prep_qkv(
    const float* __restrict__ x, const int* __restrict__ adj,
    const float* __restrict__ Wq, const float* __restrict__ Wk,
    const float* __restrict__ Wv, const float* __restrict__ Wo,
    const float* __restrict__ bq, const float* __restrict__ bk,
    const float* __restrict__ bv,
    u64* __restrict__ bmp, u16* __restrict__ Qb, u16* __restrict__ Kb,
    u16* __restrict__ Vtb, u16* __restrict__ Wob) {
  const int blk = blockIdx.x;
  if (blk < 1536) {
    qkv_unit(blk >> 9, blk & 511, x, Wq, Wk, Wv, bq, bk, bv, Qb, Kb, Vtb);
  } else if (blk < 17920) {
    adj_unit(blk - 1536, adj, bmp);
  } else {
    size_t base = ((size_t)(blk - 17920) * 256 + threadIdx.x) * 8;  // <65536
    *reinterpret_cast<short8*>(Wob + base) = fragf32(Wo + base);
  }
}

// ---------------------------------------------------------------------------
// Launch 2: attention. r11 structure + (a) pair-packed P writes (shfl_xor +
// b32 by even lanes -> 2-way banks, free) and (b) li via ones-column MFMA
// (P @ ones; kills 16 v_adds/tile + epilogue shuffle reduce).
// Block = 64 q x one bh x key-half; 4 waves x 16 rows. Grid 64x8x2.
// ---------------------------------------------------------------------------
__global__ __launch_bounds__(256) void attn_mfma(
    const u16* __restrict__ Qb, const u16* __restrict__ Kb,
    const u16* __restrict__ Vtb, const u64* __restrict__ bm,
    u16* __restrict__ Opb, float* __restrict__ Lp) {
  __shared__ u16 Ks[64 * 72];   // [key][d]
  __shared__ u16 Vs[64 * 72];   // [d][key]
  __shared__ u16 Ps[4][16 * 72];

  const int tid = threadIdx.x;
  const int wave = tid >> 6, lane = tid & 63;
  const int quad = lane >> 4, l15 = lane & 15;
  const int bh = blockIdx.y, b = bh >> 2, h = bh & 3;
  const int q0 = blockIdx.x * 64 + wave * 16;
  const int half = blockIdx.z;
  const int key0 = half * 2048;

  const u16* qr = Qb + ((size_t)bh * NN + q0 + l15) * HD + quad * 8;
  const short8 qf0 = *reinterpret_cast<const short8*>(qr);
  const short8 qf1 = *reinterpret_cast<const short8*>(qr + 32);

  short8 ones;
#pragma unroll
  for (int i = 0; i < 8; ++i) ones[i] = (short)0x3F80;  // bf16 1.0

  f32x4 Oacc[4];
#pragma unroll
  for (int i = 0; i < 4; ++i) Oacc[i] = (f32x4){0.f, 0.f, 0.f, 0.f};
  f32x4 Oli = (f32x4){0.f, 0.f, 0.f, 0.f};  // li via P @ ones
  const f32x4 z4 = {0.f, 0.f, 0.f, 0.f};
  u16* Pw = &Ps[wave][0];
  const u64* bmr = bm + ((size_t)b * NN + q0 + quad * 4) * 64 + half * 32;

  const u16* kbase = Kb + (size_t)bh * NN * HD;
  const u16* vbase = Vtb + (size_t)bh * HD * NN;
  const int rr = tid >> 3, cc8 = (tid & 7) * 8;
  const int rr2 = rr + 32;

  uint4 k0, k1, v0, v1;  // prefetch registers (tile 0)
  k0 = *reinterpret_cast<const uint4*>(kbase + (size_t)(key0 + rr) * HD + cc8);
  k1 = *reinterpret_cast<const uint4*>(kbase + (size_t)(key0 + rr2) * HD + cc8);
  v0 = *reinterpret_cast<const uint4*>(vbase + (size_t)rr * NN + key0 + cc8);
  v1 = *reinterpret_cast<const uint4*>(vbase + (size_t)rr2 * NN + key0 + cc8);

  for (int mt = 0; mt < 32; ++mt) {
    __syncthreads();
    *reinterpret_cast<uint4*>(&Ks[rr * 72 + cc8]) = k0;
    *reinterpret_cast<uint4*>(&Ks[rr2 * 72 + cc8]) = k1;
    *reinterpret_cast<uint4*>(&Vs[rr * 72 + cc8]) = v0;
    *reinterpret_cast<uint4*>(&Vs[rr2 * 72 + cc8]) = v1;
    __syncthreads();
    if (mt + 1 < 32) {  // prefetch next tile; drains during compute
      int kb2 = key0 + (mt + 1) * 64;
      k0 = *reinterpret_cast<const uint4*>(kbase + (size_t)(kb2 + rr) * HD + cc8);
      k1 = *reinterpret_cast<const uint4*>(kbase + (size_t)(kb2 + rr2) * HD + cc8);
      v0 = *reinterpret_cast<const uint4*>(vbase + (size_t)rr * NN + kb2 + cc8);
      v1 = *reinterpret_cast<const uint4*>(vbase + (size_t)rr2 * NN + kb2 + cc8);
    }

    u64 am[4];
#pragma unroll
    for (int r = 0; r < 4; ++r) am[r] = bmr[r * 64 + mt];

    // ---- QK^T + mask + exp2 + pair-packed P store ----
#pragma unroll
    for (int t = 0; t < 4; ++t) {
      const u16* kr = &Ks[(t * 16 + l15) * 72 + quad * 8];
      short8 kf0 = *reinterpret_cast<const short8*>(kr);
      short8 kf1 = *reinterpret_cast<const short8*>(kr + 32);
      f32x4 s = __builtin_amdgcn_mfma_f32_16x16x32_bf16(qf0, kf0, z4, 0, 0, 0);
      s = __builtin_amdgcn_mfma_f32_16x16x32_bf16(qf1, kf1, s, 0, 0, 0);
      const int sh = t * 16 + l15;
      float pr[4];
#pragma unroll
      for (int r = 0; r < 4; ++r)
        pr[r] = ((unsigned)(am[r] >> sh) & 1u) ? exp2f(s[r]) : 0.f;
      unsigned pk[4];
#pragma unroll
      for (int r = 0; r < 4; ++r) {
        unsigned pv = __float_as_uint(pr[r]);
        unsigned nb = __float_as_uint(__shfl_xor(pr[r], 1, 64));
        pk[r] = (pv >> 16) | (nb & 0xffff0000u);  // (sh, sh+1) bf16 pair
      }
      if ((l15 & 1) == 0) {  // even lanes write b32 pairs: 2-way banks (free)
#pragma unroll
        for (int r = 0; r < 4; ++r)
          *reinterpret_cast<unsigned*>(&Pw[(quad * 4 + r) * 72 + sh]) = pk[r];
      }
    }
    __asm__ volatile("s_waitcnt lgkmcnt(0)" ::: "memory");

    // ---- PV (+ li via ones column) ----
    const short8 pf0 = *reinterpret_cast<const short8*>(&Pw[l15 * 72 + quad * 8]);
    const short8 pf1 = *reinterpret_cast<const short8*>(&Pw[l15 * 72 + 32 + quad * 8]);
    Oli = __builtin_amdgcn_mfma_f32_16x16x32_bf16(pf0, ones, Oli, 0, 0, 0);
    Oli = __builtin_amdgcn_mfma_f32_16x16x32_bf16(pf1, ones, Oli, 0, 0, 0);
#pragma unroll
    for (int dt = 0; dt < 4; ++dt) {
      const u16* vr = &Vs[(dt * 16 + l15) * 72 + quad * 8];
      short8 vf0 = *reinterpret_cast<const short8*>(vr);
      short8 vf1 = *reinterpret_cast<const short8*>(vr + 32);
      Oacc[dt] = __builtin_amdgcn_mfma_f32_16x16x32_bf16(pf0, vf0, Oacc[dt], 0, 0, 0);
      Oacc[dt] = __builtin_amdgcn_mfma_f32_16x16x32_bf16(pf1, vf1, Oacc[dt], 0, 0, 0);
    }
  }

  // epilogue: Oli[r] already holds li for row (quad*4+r) in every lane
  u16* ob = Opb + (size_t)(half * NB + b) * NN * CDIM;
#pragma unroll
  for (int r = 0; r < 4; ++r) {
    int tok = q0 + quad * 4 + r;
    if (l15 == 0) Lp[((size_t)half * 8 + bh) * NN + tok] = Oli[r];
#pragma unroll
    for (int dt = 0; dt < 4; ++dt)
      ob[(size_t)tok * CDIM + h * HD + dt * 16 + l15] = f2bf(Oacc[dt][r]);
  }
}

// ---------------------------------------------------------------------------
// Launch 3: combine halves + output projection (MFMA) + LayerNorm.
// ---------------------------------------------------------------------------
__global__ __launch_bounds__(256) void comb_oproj(
    const u16* __restrict__ Opb, const float* __restrict__ Lp,
    const u16* __restrict__ Wob, const float* __restrict__ bo,
    const float* __restrict__ gamma, const float* __restrict__ beta,
    float* __restrict__ out) {
  __shared__ u16 As[16 * 264];
  __shared__ float ys[16][264];
  __shared__ float linv[64];
  const int tid = threadIdx.x, w = tid >> 6, lane = tid & 63;
  const int quad = lane >> 4, l15 = lane & 15;
  const int tok0 = blockIdx.x * 16;
  const int b = tok0 >> 12, nl = tok0 & 4095;

  if (tid < 64) {
    int tokr = tid >> 2, hh = tid & 3;
    int bh = b * 4 + hh;
    int n = nl + tokr;
    float s = Lp[(size_t)bh * NN + n] + Lp[(size_t)(8 + bh) * NN + n];
    linv[tokr * 4 + hh] = (s > 0.f) ? (1.f / s) : 0.f;
  }
  __syncthreads();

  {
    int tokr = tid >> 4, ch0 = (tid & 15) * 16;
    size_t base = ((size_t)b * NN + nl + tokr) * CDIM + ch0;
    uint4 a0 = *reinterpret_cast<const uint4*>(Opb + base);
    uint4 a1 = *reinterpret_cast<const uint4*>(Opb + base + 8);
    uint4 c0 = *reinterpret_cast<const uint4*>(Opb + 2097152 + base);
    uint4 c1 = *reinterpret_cast<const uint4*>(Opb + 2097152 + base + 8);
    float inv = linv[tokr * 4 + (ch0 >> 6)];
    unsigned wa[8] = {a0.x, a0.y, a0.z, a0.w, a1.x, a1.y, a1.z, a1.w};
    unsigned wb[8] = {c0.x, c0.y, c0.z, c0.w, c1.x, c1.y, c1.z, c1.w};
    u16 ov[16];
#pragma unroll
    for (int i = 0; i < 8; ++i) {
      float lo = (bf2f((u16)(wa[i] & 0xffffu)) + bf2f((u16)(wb[i] & 0xffffu))) * inv;
      float hi = (bf2f((u16)(wa[i] >> 16)) + bf2f((u16)(wb[i] >> 16))) * inv;
      ov[2 * i] = f2bf(lo);
      ov[2 * i + 1] = f2bf(hi);
    }
    u16* dst = &As[tokr * 264 + ch0];
    *reinterpret_cast<uint4*>(dst) = *reinterpret_cast<uint4*>(ov);
    *reinterpret_cast<uint4*>(dst + 8) = *reinterpret_cast<uint4*>(ov + 8);
  }
  __syncthreads();

  f32x4 acc[4];
#pragma unroll
  for (int i = 0; i < 4; ++i) acc[i] = (f32x4){0.f, 0.f, 0.f, 0.f};
#pragma unroll
  for (int ks = 0; ks < 8; ++ks) {
    short8 af = *reinterpret_cast<const short8*>(&As[l15 * 264 + ks * 32 + quad * 8]);
#pragma unroll
    for (int ns = 0; ns < 4; ++ns) {
      short8 bf = *reinterpret_cast<const short8*>(
          &Wob[(size_t)(w * 64 + ns * 16 + l15) * 256 + ks * 32 + quad * 8]);
      acc[ns] = __builtin_amdgcn_mfma_f32_16x16x32_bf16(af, bf, acc[ns], 0, 0, 0);
    }
  }

#pragma unroll
  for (int ns = 0; ns < 4; ++ns) {
    int ch = w * 64 + ns * 16 + l15;
    float bb = bo[ch];
#pragma unroll
    for (int r = 0; r < 4; ++r) ys[quad * 4 + r][ch] = acc[ns][r] + bb;
  }
  __syncthreads();

  float g[4], bt[4];
#pragma unroll
  for (int i = 0; i < 4; ++i) {
    g[i] = gamma[lane + i * 64];
    bt[i] = beta[lane + i * 64];
  }
#pragma unroll
  for (int rr = 0; rr < 4; ++rr) {
    int r = w * 4 + rr;
    float v[4], s = 0.f, s2 = 0.f;
#pragma unroll
    for (int i = 0; i < 4; ++i) {
      v[i] = ys[r][lane + i * 64];
      s += v[i];
      s2 = fmaf(v[i], v[i], s2);
    }
#pragma unroll
    for (int off = 32; off > 0; off >>= 1) {
      s += __shfl_xor(s, off, 64);
      s2 += __shfl_xor(s2, off, 64);
    }
    float mu = s * (1.f / 256.f);
    float rs = rsqrtf(s2 * (1.f / 256.f) - mu * mu + 1e-5f);
    float* orow = out + (size_t)(tok0 + r) * 256;
#pragma unroll
    for (int i = 0; i < 4; ++i)
      orow[lane + i * 64] = (v[i] - mu) * rs * g[i] + bt[i];
  }
}

// ---------------------------------------------------------------------------
extern "C" void kernel_launch(void* const* d_in, const int* in_sizes, int n_in,
                              void* d_out, int out_size, void* d_ws, size_t ws_size,
                              hipStream_t stream) {
  const float* x     = (const float*)d_in[0];
  const int*   adj   = (const int*)d_in[1];
  const float* Wq    = (const float*)d_in[2];
  const float* bq    = (const float*)d_in[3];
  const float* Wk    = (const float*)d_in[4];
  const float* bk    = (const float*)d_in[5];
  const float* Wv    = (const float*)d_in[6];
  const float* bv    = (const float*)d_in[7];
  const float* Wo    = (const float*)d_in[8];
  const float* bo    = (const float*)d_in[9];
  const float* gamma = (const float*)d_in[10];
  const float* beta  = (const float*)d_in[11];
  float* out = (float*)d_out;

  const size_t PER = (size_t)NB * HEADS * NN * HD;  // 2,097,152
  u16* Wob = (u16*)d_ws;                 // 65,536
  u64* bmp = (u64*)(Wob + 65536);        // 524,288 u64 (4 MB), 8B-aligned
  u16* Qb  = (u16*)(bmp + 524288);
  u16* Kb  = Qb + PER;
  u16* Vtb = Kb + PER;
  u16* Opb = Vtb + PER;                  // 2 x PER bf16
  float* Lp = (float*)(Opb + 2 * PER);   // 65,536 fp32

  const size_t NEED = (size_t)((u16*)(Lp + 65536) - (u16*)d_ws) * sizeof(u16);
  if (ws_size < NEED) return;

  l1_prep_qkv<<<dim3(17952), dim3(256), 0, stream>>>(
      x, adj, Wq, Wk, Wv, Wo, bq, bk, bv, bmp, Qb, Kb, Vtb, Wob);

  attn_mfma<<<dim3(NN / 64, NB * HEADS, 2), dim3(256), 0, stream>>>(
      Qb, Kb, Vtb, bmp, Opb, Lp);

  comb_oproj<<<dim3((NB * NN) / 16), dim3(256), 0, stream>>>(
      Opb, Lp, Wob, bo, gamma, beta, out);
}

// Round 14
// 350.516 us; speedup vs baseline: 2.1813x; 1.0876x over previous
//
#include <hip/hip_runtime.h>
#include <stdint.h>

// GraphAttention: B=2, N=4096, C=256, H=4, D=64. Inputs fp32, adj int32,
// OUTPUT FP32 (proven r6/r7). Threshold = 2% of ref absmax = 0.0609.
// Fixed harness overhead ~175us (measured r12). attn improvements (pair-
// packed P, ones-li) kept from r13; prep/qkv reverted to split (r13 merge
// was latency-bound: redundant W conv + serialized ballot loop).
#define CDIM 256
#define HEADS 4
#define HD 64
#define NB 2
#define NN 4096

typedef unsigned short u16;
typedef unsigned char u8;
typedef unsigned long long u64;
typedef __attribute__((ext_vector_type(8))) short short8;   // bf16x8 frag
typedef __attribute__((ext_vector_type(4))) float f32x4;    // C/D frag

// 0.125 (1/sqrt(64)) * log2(e): folded into Q so softmax uses exp2
#define QSCALE 0.1803368801111244f

__device__ __forceinline__ u16 f2bf(float f) {  // RNE
  union { float f; unsigned u; } v; v.f = f;
  return (u16)((v.u + 0x7fffu + ((v.u >> 16) & 1u)) >> 16);
}
__device__ __forceinline__ float bf2f(u16 u) {
  union { unsigned u; float f; } v; v.u = ((unsigned)u) << 16; return v.f;
}
// load MFMA frag from fp32 global, converting to bf16 in-reg
__device__ __forceinline__ short8 fragf32(const float* p) {
  float4 a = reinterpret_cast<const float4*>(p)[0];
  float4 b = reinterpret_cast<const float4*>(p)[1];
  short8 h;
  h[0] = (short)f2bf(a.x); h[1] = (short)f2bf(a.y);
  h[2] = (short)f2bf(a.z); h[3] = (short)f2bf(a.w);
  h[4] = (short)f2bf(b.x); h[5] = (short)f2bf(b.y);
  h[6] = (short)f2bf(b.z); h[7] = (short)f2bf(b.w);
  return h;
}

// ---------------------------------------------------------------------------
// Launch 1: prep. Blocks 0..4095: adj -> bitmask, streaming (no ballot):
// lane packs 8 keys into one byte, 64B coalesced byte-store per wave,
// 4 independent chunk-iterations per wave (loads all independent).
// bm bytes: row*512 + (chunk&7)*64 + lane; bit j = key (lane*8+j) (LE).
// Blocks 4096..4223: W fp32->bf16 (4 matrices, 2048 elems/block).
// ---------------------------------------------------------------------------
__global__ __launch_bounds__(256) void prep(
    const int* __restrict__ adj, u8* __restrict__ bmb,
    const float* __restrict__ Wq, const float* __restrict__ Wk,
    const float* __restrict__ Wv, const float* __restrict__ Wo,
    u16* __restrict__ Wqb, u16* __restrict__ Wkb,
    u16* __restrict__ Wvb, u16* __restrict__ Wob) {
  const int blk = blockIdx.x;
  if (blk < 4096) {
    const int wave = threadIdx.x >> 6, lane = threadIdx.x & 63;
    const int c0 = blk * 16 + wave * 4;  // 4 chunks of 512 keys per wave
#pragma unroll
    for (int it = 0; it < 4; ++it) {
      int c = c0 + it;
      int row = c >> 3, kb = (c & 7) * 512;
      const int* src = adj + (size_t)row * 4096 + kb + lane * 8;
      uint4 a = *reinterpret_cast<const uint4*>(src);
      uint4 b = *reinterpret_cast<const uint4*>(src + 4);
      unsigned byte = 0;
      byte |= (a.x != 0) ? 1u : 0u;
      byte |= (a.y != 0) ? 2u : 0u;
      byte |= (a.z != 0) ? 4u : 0u;
      byte |= (a.w != 0) ? 8u : 0u;
      byte |= (b.x != 0) ? 16u : 0u;
      byte |= (b.y != 0) ? 32u : 0u;
      byte |= (b.z != 0) ? 64u : 0u;
      byte |= (b.w != 0) ? 128u : 0u;
      bmb[(size_t)row * 512 + (c & 7) * 64 + lane] = (u8)byte;
    }
  } else {
    size_t base = ((size_t)(blk - 4096) * 256 + threadIdx.x) * 8;  // <262144
    int w = (int)(base >> 16);
    size_t lo = base & 65535;
    const float* src;
    u16* dst;
    if (w == 0)      { src = Wq + lo; dst = Wqb + lo; }
    else if (w == 1) { src = Wk + lo; dst = Wkb + lo; }
    else if (w == 2) { src = Wv + lo; dst = Wvb + lo; }
    else             { src = Wo + lo; dst = Wob + lo; }
    *reinterpret_cast<short8*>(dst) = fragf32(src);
  }
}

// ---------------------------------------------------------------------------
// Launch 2: fused QKV projection (MFMA). Grid (512, 3). x read fp32 and
// converted in-reg; W read bf16 (prep). y=0: Qb=(x@Wq^T+bq)*QSCALE;
// y=1: Kb=x@Wk^T+bk; y=2: Vtb[bh][d][n]=Wv@x^T+bv (transposed output).
// ---------------------------------------------------------------------------
__global__ __launch_bounds__(256) void qkv_gemm(
    const float* __restrict__ x,
    const u16* __restrict__ Wqb, const u16* __restrict__ Wkb,
    const u16* __restrict__ Wvb,
    const float* __restrict__ bq, const float* __restrict__ bk,
    const float* __restrict__ bv,
    u16* __restrict__ Qb, u16* __restrict__ Kb, u16* __restrict__ Vtb) {
  const int tid = threadIdx.x, w = tid >> 6, lane = tid & 63;
  const int quad = lane >> 4, l15 = lane & 15;
  const int tok0 = blockIdx.x * 16;
  const int b = tok0 >> 12, nl = tok0 & 4095;
  const int ym = blockIdx.y;

  f32x4 acc[4];
#pragma unroll
  for (int i = 0; i < 4; ++i) acc[i] = (f32x4){0.f, 0.f, 0.f, 0.f};

  if (ym < 2) {
    const u16* Wb = (ym == 0) ? Wqb : Wkb;
    const float* bias = (ym == 0) ? bq : bk;
    const float scale = (ym == 0) ? QSCALE : 1.0f;
    u16* outp = (ym == 0) ? Qb : Kb;
#pragma unroll
    for (int ks = 0; ks < 8; ++ks) {
      short8 af = fragf32(x + (size_t)(tok0 + l15) * 256 + ks * 32 + quad * 8);
#pragma unroll
      for (int ns = 0; ns < 4; ++ns) {
        short8 bf = *reinterpret_cast<const short8*>(
            &Wb[(size_t)(w * 64 + ns * 16 + l15) * 256 + ks * 32 + quad * 8]);
        acc[ns] = __builtin_amdgcn_mfma_f32_16x16x32_bf16(af, bf, acc[ns], 0, 0, 0);
      }
    }
#pragma unroll
    for (int ns = 0; ns < 4; ++ns) {
      int d = ns * 16 + l15;
      float bb = bias[w * 64 + d];
#pragma unroll
      for (int r = 0; r < 4; ++r) {
        int tok = nl + quad * 4 + r;
        outp[((size_t)(b * HEADS + w) * NN + tok) * HD + d] =
            f2bf((acc[ns][r] + bb) * scale);
      }
    }
  } else {
#pragma unroll
    for (int ks = 0; ks < 8; ++ks) {
      short8 xf = fragf32(x + (size_t)(tok0 + l15) * 256 + ks * 32 + quad * 8);
#pragma unroll
      for (int ms = 0; ms < 4; ++ms) {
        short8 wf = *reinterpret_cast<const short8*>(
            &Wvb[(size_t)(w * 64 + ms * 16 + l15) * 256 + ks * 32 + quad * 8]);
        acc[ms] = __builtin_amdgcn_mfma_f32_16x16x32_bf16(wf, xf, acc[ms], 0, 0, 0);
      }
    }
#pragma unroll
    for (int ms = 0; ms < 4; ++ms) {
#pragma unroll
      for (int r = 0; r < 4; ++r) {
        int d = ms * 16 + quad * 4 + r;
        float bb = bv[w * 64 + d];
        Vtb[((size_t)((b * HEADS + w) * HD + d)) * NN + nl + l15] =
            f2bf(acc[ms][r] + bb);
      }
    }
  }
}

// ---------------------------------------------------------------------------
// Launch 3: attention (r13-proven). Pair-packed P writes (2-way banks =
// free), li via ones-column MFMA. Block = 64 q x one bh x key-half;
// 4 waves x 16 rows. Grid 64x8x2.
// ---------------------------------------------------------------------------
__global__ __launch_bounds__(256) void attn_mfma(
    const u16* __restrict__ Qb, const u16* __restrict__ Kb,
    const u16* __restrict__ Vtb, const u64* __restrict__ bm,
    u16* __restrict__ Opb, float* __restrict__ Lp) {
  __shared__ u16 Ks[64 * 72];   // [key][d]
  __shared__ u16 Vs[64 * 72];   // [d][key]
  __shared__ u16 Ps[4][16 * 72];

  const int tid = threadIdx.x;
  const int wave = tid >> 6, lane = tid & 63;
  const int quad = lane >> 4, l15 = lane & 15;
  const int bh = blockIdx.y, b = bh >> 2, h = bh & 3;
  const int q0 = blockIdx.x * 64 + wave * 16;
  const int half = blockIdx.z;
  const int key0 = half * 2048;

  const u16* qr = Qb + ((size_t)bh * NN + q0 + l15) * HD + quad * 8;
  const short8 qf0 = *reinterpret_cast<const short8*>(qr);
  const short8 qf1 = *reinterpret_cast<const short8*>(qr + 32);

  short8 ones;
#pragma unroll
  for (int i = 0; i < 8; ++i) ones[i] = (short)0x3F80;  // bf16 1.0

  f32x4 Oacc[4];
#pragma unroll
  for (int i = 0; i < 4; ++i) Oacc[i] = (f32x4){0.f, 0.f, 0.f, 0.f};
  f32x4 Oli = (f32x4){0.f, 0.f, 0.f, 0.f};  // li via P @ ones
  const f32x4 z4 = {0.f, 0.f, 0.f, 0.f};
  u16* Pw = &Ps[wave][0];
  const u64* bmr = bm + ((size_t)b * NN + q0 + quad * 4) * 64 + half * 32;

  const u16* kbase = Kb + (size_t)bh * NN * HD;
  const u16* vbase = Vtb + (size_t)bh * HD * NN;
  const int rr = tid >> 3, cc8 = (tid & 7) * 8;
  const int rr2 = rr + 32;

  uint4 k0, k1, v0, v1;  // prefetch registers (tile 0)
  k0 = *reinterpret_cast<const uint4*>(kbase + (size_t)(key0 + rr) * HD + cc8);
  k1 = *reinterpret_cast<const uint4*>(kbase + (size_t)(key0 + rr2) * HD + cc8);
  v0 = *reinterpret_cast<const uint4*>(vbase + (size_t)rr * NN + key0 + cc8);
  v1 = *reinterpret_cast<const uint4*>(vbase + (size_t)rr2 * NN + key0 + cc8);

  for (int mt = 0; mt < 32; ++mt) {
    __syncthreads();
    *reinterpret_cast<uint4*>(&Ks[rr * 72 + cc8]) = k0;
    *reinterpret_cast<uint4*>(&Ks[rr2 * 72 + cc8]) = k1;
    *reinterpret_cast<uint4*>(&Vs[rr * 72 + cc8]) = v0;
    *reinterpret_cast<uint4*>(&Vs[rr2 * 72 + cc8]) = v1;
    __syncthreads();
    if (mt + 1 < 32) {  // prefetch next tile; drains during compute
      int kb2 = key0 + (mt + 1) * 64;
      k0 = *reinterpret_cast<const uint4*>(kbase + (size_t)(kb2 + rr) * HD + cc8);
      k1 = *reinterpret_cast<const uint4*>(kbase + (size_t)(kb2 + rr2) * HD + cc8);
      v0 = *reinterpret_cast<const uint4*>(vbase + (size_t)rr * NN + kb2 + cc8);
      v1 = *reinterpret_cast<const uint4*>(vbase + (size_t)rr2 * NN + kb2 + cc8);
    }

    u64 am[4];
#pragma unroll
    for (int r = 0; r < 4; ++r) am[r] = bmr[r * 64 + mt];

    // ---- QK^T + mask + exp2 + pair-packed P store ----
#pragma unroll
    for (int t = 0; t < 4; ++t) {
      const u16* kr = &Ks[(t * 16 + l15) * 72 + quad * 8];
      short8 kf0 = *reinterpret_cast<const short8*>(kr);
      short8 kf1 = *reinterpret_cast<const short8*>(kr + 32);
      f32x4 s = __builtin_amdgcn_mfma_f32_16x16x32_bf16(qf0, kf0, z4, 0, 0, 0);
      s = __builtin_amdgcn_mfma_f32_16x16x32_bf16(qf1, kf1, s, 0, 0, 0);
      const int sh = t * 16 + l15;
      float pr[4];
#pragma unroll
      for (int r = 0; r < 4; ++r)
        pr[r] = ((unsigned)(am[r] >> sh) & 1u) ? exp2f(s[r]) : 0.f;
      unsigned pk[4];
#pragma unroll
      for (int r = 0; r < 4; ++r) {
        unsigned pv = __float_as_uint(pr[r]);
        unsigned nb = __float_as_uint(__shfl_xor(pr[r], 1, 64));
        pk[r] = (pv >> 16) | (nb & 0xffff0000u);  // (sh, sh+1) bf16 pair
      }
      if ((l15 & 1) == 0) {  // even lanes write b32 pairs: 2-way banks (free)
#pragma unroll
        for (int r = 0; r < 4; ++r)
          *reinterpret_cast<unsigned*>(&Pw[(quad * 4 + r) * 72 + sh]) = pk[r];
      }
    }
    __asm__ volatile("s_waitcnt lgkmcnt(0)" ::: "memory");

    // ---- PV (+ li via ones column) ----
    const short8 pf0 = *reinterpret_cast<const short8*>(&Pw[l15 * 72 + quad * 8]);
    const short8 pf1 = *reinterpret_cast<const short8*>(&Pw[l15 * 72 + 32 + quad * 8]);
    Oli = __builtin_amdgcn_mfma_f32_16x16x32_bf16(pf0, ones, Oli, 0, 0, 0);
    Oli = __builtin_amdgcn_mfma_f32_16x16x32_bf16(pf1, ones, Oli, 0, 0, 0);
#pragma unroll
    for (int dt = 0; dt < 4; ++dt) {
      const u16* vr = &Vs[(dt * 16 + l15) * 72 + quad * 8];
      short8 vf0 = *reinterpret_cast<const short8*>(vr);
      short8 vf1 = *reinterpret_cast<const short8*>(vr + 32);
      Oacc[dt] = __builtin_amdgcn_mfma_f32_16x16x32_bf16(pf0, vf0, Oacc[dt], 0, 0, 0);
      Oacc[dt] = __builtin_amdgcn_mfma_f32_16x16x32_bf16(pf1, vf1, Oacc[dt], 0, 0, 0);
    }
  }

  // epilogue: Oli[r] holds li for row (quad*4+r) in every lane
  u16* ob = Opb + (size_t)(half * NB + b) * NN * CDIM;
#pragma unroll
  for (int r = 0; r < 4; ++r) {
    int tok = q0 + quad * 4 + r;
    if (l15 == 0) Lp[((size_t)half * 8 + bh) * NN + tok] = Oli[r];
#pragma unroll
    for (int dt = 0; dt < 4; ++dt)
      ob[(size_t)tok * CDIM + h * HD + dt * 16 + l15] = f2bf(Oacc[dt][r]);
  }
}

// ---------------------------------------------------------------------------
// Launch 4: combine halves + output projection (MFMA) + LayerNorm.
// ---------------------------------------------------------------------------
__global__ __launch_bounds__(256) void comb_oproj(
    const u16* __restrict__ Opb, const float* __restrict__ Lp,
    const u16* __restrict__ Wob, const float* __restrict__ bo,
    const float* __restrict__ gamma, const float* __restrict__ beta,
    float* __restrict__ out) {
  __shared__ u16 As[16 * 264];
  __shared__ float ys[16][264];
  __shared__ float linv[64];
  const int tid = threadIdx.x, w = tid >> 6, lane = tid & 63;
  const int quad = lane >> 4, l15 = lane & 15;
  const int tok0 = blockIdx.x * 16;
  const int b = tok0 >> 12, nl = tok0 & 4095;

  if (tid < 64) {
    int tokr = tid >> 2, hh = tid & 3;
    int bh = b * 4 + hh;
    int n = nl + tokr;
    float s = Lp[(size_t)bh * NN + n] + Lp[(size_t)(8 + bh) * NN + n];
    linv[tokr * 4 + hh] = (s > 0.f) ? (1.f / s) : 0.f;
  }
  __syncthreads();

  {
    int tokr = tid >> 4, ch0 = (tid & 15) * 16;
    size_t base = ((size_t)b * NN + nl + tokr) * CDIM + ch0;
    uint4 a0 = *reinterpret_cast<const uint4*>(Opb + base);
    uint4 a1 = *reinterpret_cast<const uint4*>(Opb + base + 8);
    uint4 c0 = *reinterpret_cast<const uint4*>(Opb + 2097152 + base);
    uint4 c1 = *reinterpret_cast<const uint4*>(Opb + 2097152 + base + 8);
    float inv = linv[tokr * 4 + (ch0 >> 6)];
    unsigned wa[8] = {a0.x, a0.y, a0.z, a0.w, a1.x, a1.y, a1.z, a1.w};
    unsigned wb[8] = {c0.x, c0.y, c0.z, c0.w, c1.x, c1.y, c1.z, c1.w};
    u16 ov[16];
#pragma unroll
    for (int i = 0; i < 8; ++i) {
      float lo = (bf2f((u16)(wa[i] & 0xffffu)) + bf2f((u16)(wb[i] & 0xffffu))) * inv;
      float hi = (bf2f((u16)(wa[i] >> 16)) + bf2f((u16)(wb[i] >> 16))) * inv;
      ov[2 * i] = f2bf(lo);
      ov[2 * i + 1] = f2bf(hi);
    }
    u16* dst = &As[tokr * 264 + ch0];
    *reinterpret_cast<uint4*>(dst) = *reinterpret_cast<uint4*>(ov);
    *reinterpret_cast<uint4*>(dst + 8) = *reinterpret_cast<uint4*>(ov + 8);
  }
  __syncthreads();

  f32x4 acc[4];
#pragma unroll
  for (int i = 0; i < 4; ++i) acc[i] = (f32x4){0.f, 0.f, 0.f, 0.f};
#pragma unroll
  for (int ks = 0; ks < 8; ++ks) {
    short8 af = *reinterpret_cast<const short8*>(&As[l15 * 264 + ks * 32 + quad * 8]);
#pragma unroll
    for (int ns = 0; ns < 4; ++ns) {
      short8 bf = *reinterpret_cast<const short8*>(
          &Wob[(size_t)(w * 64 + ns * 16 + l15) * 256 + ks * 32 + quad * 8]);
      acc[ns] = __builtin_amdgcn_mfma_f32_16x16x32_bf16(af, bf, acc[ns], 0, 0, 0);
    }
  }

#pragma unroll
  for (int ns = 0; ns < 4; ++ns) {
    int ch = w * 64 + ns * 16 + l15;
    float bb = bo[ch];
#pragma unroll
    for (int r = 0; r < 4; ++r) ys[quad * 4 + r][ch] = acc[ns][r] + bb;
  }
  __syncthreads();

  float g[4], bt[4];
#pragma unroll
  for (int i = 0; i < 4; ++i) {
    g[i] = gamma[lane + i * 64];
    bt[i] = beta[lane + i * 64];
  }
#pragma unroll
  for (int rr = 0; rr < 4; ++rr) {
    int r = w * 4 + rr;
    float v[4], s = 0.f, s2 = 0.f;
#pragma unroll
    for (int i = 0; i < 4; ++i) {
      v[i] = ys[r][lane + i * 64];
      s += v[i];
      s2 = fmaf(v[i], v[i], s2);
    }
#pragma unroll
    for (int off = 32; off > 0; off >>= 1) {
      s += __shfl_xor(s, off, 64);
      s2 += __shfl_xor(s2, off, 64);
    }
    float mu = s * (1.f / 256.f);
    float rs = rsqrtf(s2 * (1.f / 256.f) - mu * mu + 1e-5f);
    float* orow = out + (size_t)(tok0 + r) * 256;
#pragma unroll
    for (int i = 0; i < 4; ++i)
      orow[lane + i * 64] = (v[i] - mu) * rs * g[i] + bt[i];
  }
}

// ---------------------------------------------------------------------------
extern "C" void kernel_launch(void* const* d_in, const int* in_sizes, int n_in,
                              void* d_out, int out_size, void* d_ws, size_t ws_size,
                              hipStream_t stream) {
  const float* x     = (const float*)d_in[0];
  const int*   adj   = (const int*)d_in[1];
  const float* Wq    = (const float*)d_in[2];
  const float* bq    = (const float*)d_in[3];
  const float* Wk    = (const float*)d_in[4];
  const float* bk    = (const float*)d_in[5];
  const float* Wv    = (const float*)d_in[6];
  const float* bv    = (const float*)d_in[7];
  const float* Wo    = (const float*)d_in[8];
  const float* bo    = (const float*)d_in[9];
  const float* gamma = (const float*)d_in[10];
  const float* beta  = (const float*)d_in[11];
  float* out = (float*)d_out;

  const size_t PER = (size_t)NB * HEADS * NN * HD;  // 2,097,152
  u16* Wqb = (u16*)d_ws;                 // 65,536 each
  u16* Wkb = Wqb + 65536;
  u16* Wvb = Wkb + 65536;
  u16* Wob = Wvb + 65536;
  u64* bmp = (u64*)(Wob + 65536);        // 524,288 u64 (4 MB), 8B-aligned
  u16* Qb  = (u16*)(bmp + 524288);
  u16* Kb  = Qb + PER;
  u16* Vtb = Kb + PER;
  u16* Opb = Vtb + PER;                  // 2 x PER bf16
  float* Lp = (float*)(Opb + 2 * PER);   // 65,536 fp32

  const size_t NEED = (size_t)((u16*)(Lp + 65536) - (u16*)d_ws) * sizeof(u16);
  if (ws_size < NEED) return;

  prep<<<dim3(4224), dim3(256), 0, stream>>>(
      adj, (u8*)bmp, Wq, Wk, Wv, Wo, Wqb, Wkb, Wvb, Wob);

  qkv_gemm<<<dim3(512, 3), dim3(256), 0, stream>>>(
      x, Wqb, Wkb, Wvb, bq, bk, bv, Qb, Kb, Vtb);

  attn_mfma<<<dim3(NN / 64, NB * HEADS, 2), dim3(256), 0, stream>>>(
      Qb, Kb, Vtb, bmp, Opb, Lp);

  comb_oproj<<<dim3((NB * NN) / 16), dim3(256), 0, stream>>>(
      Opb, Lp, Wob, bo, gamma, beta, out);
}